// Round 17
// baseline (63.670 us; speedup 1.0000x reference)
//
#include <hip/hip_runtime.h>
#include <hip/hip_fp16.h>

#define Hdim 128
#define Wdim 128
#define Cdim 64
#define HW   (Hdim * Wdim)
#define NPIX (4 * HW)     // 65536
#define NBLK (NPIX / 64)  // 1024 blocks / tiles, 64 pixels each
#define NXCD 8
#define Hp 130            // padded dims
#define HWp (Hp * Hp)     // 16900

typedef _Float16 v8h __attribute__((ext_vector_type(8)));
typedef float    v4f __attribute__((ext_vector_type(4)));

// XCD-aware bijective swizzle (nwg % 8 == 0): consecutive logical blocks
// (which share image rows -> xt reuse) land on the SAME XCD's L2.
__device__ __forceinline__ int xcd_swizzle(int bid, int nblk) {
    return (bid % NXCD) * (nblk / NXCD) + bid / NXCD;
}

// geo layout: [group = pixel>>3][k:9][i:8 px][8 dwords {w0..w3, i0..i3}]

// ---------------------------------------------------------------------------
// Kernel A: fused {NCHW->padded-NHWC-fp16 transpose} + {offset conv dw3x3 +
// pw 64->18} + {sampling geometry}.  (unchanged from R14/R16)
// ---------------------------------------------------------------------------
__global__ __launch_bounds__(512) void offset_geo_kernel(
    const float* __restrict__ x,     // (B, C, H, W)
    const float* __restrict__ p_dw,  // (C, 1, 3, 3)
    const float* __restrict__ p_pw,  // (18, C, 1, 1)
    __half* __restrict__ xt,         // (B, 130, 130, C) padded NHWC fp16
    float* __restrict__ geo)         // (8192, 9, 8, 8) dwords
{
    __shared__ float part[8][18][64];   // 36.8 KB; part[0] reused as sum

    int lane = threadIdx.x & 63;
    int g    = threadIdx.x >> 6;
    int blk  = xcd_swizzle(blockIdx.x, NBLK);
    int pix0 = blk * 64;
    int pix  = pix0 + lane;
    int w = pix & (Wdim - 1);
    int h = (pix >> 7) & (Hdim - 1);
    int b = pix >> 14;

    // --- zero the pad ring of xt (2064 ring positions x 128 B) -----------
    {
        int gid = blockIdx.x * 512 + threadIdx.x;   // raw id: blocks 0..32
        if (gid < 2064 * 8) {
            int rp  = gid >> 3, sub = gid & 7;
            int img = rp / 516, pos = rp - img * 516;
            int i, j;
            if (pos < 130)      { i = 0;   j = pos; }
            else if (pos < 260) { i = 129; j = pos - 130; }
            else { int p2 = pos - 260; i = 1 + (p2 >> 1); j = (p2 & 1) ? 129 : 0; }
            float4* dst = (float4*)(xt + ((size_t)img * HWp + i * Hp + j) * Cdim);
            dst[sub] = make_float4(0.f, 0.f, 0.f, 0.f);
        }
    }

    // --- depthwise 3x3: masks/offsets hoisted out of the channel loop ----
    int   off9[9];
    float msk9[9];
#pragma unroll
    for (int dh = -1; dh <= 1; ++dh) {
#pragma unroll
        for (int dw = -1; dw <= 1; ++dw) {
            int tap = (dh + 1) * 3 + (dw + 1);
            int hh = h + dh, ww = w + dw;
            bool ok = (hh >= 0) & (hh < Hdim) & (ww >= 0) & (ww < Wdim);
            off9[tap] = ok ? hh * Wdim + ww : 0;
            msk9[tap] = ok ? 1.f : 0.f;
        }
    }

    float t[8], ctr[8];
#pragma unroll
    for (int i = 0; i < 8; ++i) {
        int c = g * 8 + i;              // wave-uniform
        const float* xb = x + (size_t)(b * Cdim + c) * HW;
        float s = 0.f;
#pragma unroll
        for (int tap = 0; tap < 9; ++tap) {
            float v = xb[off9[tap]] * msk9[tap];
            s += v * p_dw[c * 9 + tap];
        }
        t[i]   = s;
        ctr[i] = xb[h * Wdim + w];      // transpose source (center tap)
    }

    // --- transpose write: 8 channels -> 4x half2 packed in one 16B store --
    {
        __half2 h0 = __floats2half2_rn(ctr[0], ctr[1]);
        __half2 h1 = __floats2half2_rn(ctr[2], ctr[3]);
        __half2 h2 = __floats2half2_rn(ctr[4], ctr[5]);
        __half2 h3 = __floats2half2_rn(ctr[6], ctr[7]);
        uint4 pk;
        pk.x = *(const unsigned int*)&h0;
        pk.y = *(const unsigned int*)&h1;
        pk.z = *(const unsigned int*)&h2;
        pk.w = *(const unsigned int*)&h3;
        size_t ppos = ((size_t)b * HWp + (h + 1) * Hp + (w + 1)) * Cdim + g * 8;
        *(uint4*)(xt + ppos) = pk;      // 16B-aligned (g*8 halves)
    }

    // --- pointwise 64->18 partials -> LDS ---------------------------------
#pragma unroll
    for (int j = 0; j < 18; ++j) {
        float s = 0.f;
#pragma unroll
        for (int i = 0; i < 8; ++i)
            s += p_pw[j * Cdim + g * 8 + i] * t[i];
        part[g][j][lane] = s;
    }
    __syncthreads();

    // reduce 8 partials into part[0]
#pragma unroll
    for (int it = 0; it < 3; ++it) {
        int idx = threadIdx.x + it * 512;
        if (idx < 18 * 64) {
            int j = idx >> 6;
            int p = idx & 63;
            float s = part[0][j][p];
#pragma unroll
            for (int q = 1; q < 8; ++q) s += part[q][j][p];
            part[0][j][p] = s;
        }
    }
    __syncthreads();

    // --- geometry pass: reference formulas verbatim on the padded grid ---
#pragma unroll
    for (int it = 0; it < 2; ++it) {
        int idx = threadIdx.x + it * 512;
        if (idx < 9 * 64) {
            int k = idx >> 6;
            int p = idx & 63;
            int ppix = pix0 + p;
            int pw2 = ppix & (Wdim - 1);
            int ph2 = (ppix >> 7) & (Hdim - 1);

            float px = (float)(ph2 + 1) + (float)(k / 3 - 1) + part[0][k][p];
            float py = (float)(pw2 + 1) + (float)(k % 3 - 1) + part[0][k + 9][p];

            float fx = floorf(px), fy = floorf(py);
            float ltx = fminf(fmaxf(fx, 0.f), 129.f);
            float lty = fminf(fmaxf(fy, 0.f), 129.f);
            float rbx = fminf(fmaxf(fx + 1.f, 0.f), 129.f);
            float rby = fminf(fmaxf(fy + 1.f, 0.f), 129.f);
            float pxc = fminf(fmaxf(px, 0.f), 129.f);
            float pyc = fminf(fmaxf(py, 0.f), 129.f);

            float glt = (1.f + ltx - pxc) * (1.f + lty - pyc);
            float grb = (1.f - rbx + pxc) * (1.f - rby + pyc);
            float glb = (1.f + ltx - pxc) * (1.f - rby + pyc);
            float grt = (1.f - rbx + pxc) * (1.f + lty - pyc);

            int ix0 = (int)ltx, iy0 = (int)lty, ix1 = (int)rbx, iy1 = (int)rby;

            // entry = (group*9 + k)*8 + i   (group = pixel>>3)
            size_t e = (((size_t)blk * 8 + (p >> 3)) * 9 + k) * 8 + (p & 7);
            float4* wdst = (float4*)(geo + e * 8);
            int4*   idst = (int4*)(geo + e * 8 + 4);
            *wdst = make_float4(glt, grb, glb, grt);
            *idst = make_int4(ix0 * Hp + iy0,   // lt
                              ix1 * Hp + iy1,   // rb
                              ix0 * Hp + iy1,   // lb
                              ix1 * Hp + iy0);  // rt
        }
    }
}

// ---------------------------------------------------------------------------
// Kernel B: deformable sampling + collapsed depthwise + MFMA pointwise.
// R17: phase A software-pipelined in batches of 4 pixels — ALL 16 corner
// loads of the batch are issued into a register array BEFORE any compute,
// raising in-flight loads per wave ~2 -> 16 (R16's VGPR=56 left no room;
// the unexplained ~20us of deform = exposed L2 latency on a ~2-deep
// pipeline). Costs ~16 VGPR (~7 waves/SIMD vs 8).
// Phase B: MFMA pointwise (unchanged from R16).
// ---------------------------------------------------------------------------
__global__ __launch_bounds__(512) void deform_kernel(
    const __half* __restrict__ xt,   // (B, 130, 130, C) padded NHWC fp16
    const float* __restrict__ c_dw,  // (C, 1, 3, 3)
    const float* __restrict__ c_pw,  // (C, C, 1, 1)
    const int* __restrict__ geo,     // (8192, 9, 8, 8) dwords
    float* __restrict__ out)         // (B, C, H, W)
{
    __shared__ _Float16 accs_h[64][72];  // [pixel][channel] 9.2 KB
    __shared__ float    outD[64][69];    // [pixel][oc] 17.6 KB

    int lane = threadIdx.x & 63;
    int gu   = __builtin_amdgcn_readfirstlane(threadIdx.x >> 6);
    int blk  = xcd_swizzle(blockIdx.x, NBLK);
    int pix0 = blk * 64;
    int b    = pix0 >> 14;           // block-uniform
    const __half* xb = xt + (size_t)b * HWp * Cdim;

    // prefetch this wave's geometry: 576 dwords -> 9 VGPRs per lane
    int gv0, gv1, gv2, gv3, gv4, gv5, gv6, gv7, gv8;
    {
        const int* gb = geo + ((size_t)blk * 8 + gu) * 576 + lane;
        gv0 = gb[0];   gv1 = gb[64];  gv2 = gb[128];
        gv3 = gb[192]; gv4 = gb[256]; gv5 = gb[320];
        gv6 = gb[384]; gv7 = gb[448]; gv8 = gb[512];
    }
    // per-lane depthwise weights (lane = channel)
    float wk9[9];
#pragma unroll
    for (int k = 0; k < 9; ++k) wk9[k] = c_dw[lane * 9 + k];

#define GV(r) ((r)==0?gv0:(r)==1?gv1:(r)==2?gv2:(r)==3?gv3:(r)==4?gv4: \
               (r)==5?gv5:(r)==6?gv6:(r)==7?gv7:gv8)
#define RL(f) __builtin_amdgcn_readlane(GV((f) >> 6), (f) & 63)

    float acc[8];
#pragma unroll
    for (int i = 0; i < 8; ++i) acc[i] = 0.f;

#pragma unroll
    for (int k = 0; k < 9; ++k) {
#pragma unroll
        for (int ih = 0; ih < 2; ++ih) {
            // --- stage: issue ALL 16 loads of this 4-pixel batch ---------
            __half hv[16];
#pragma unroll
            for (int q = 0; q < 4; ++q) {
                const int f = (k * 8 + ih * 4 + q) * 8;
                hv[q * 4 + 0] = (xb + (size_t)RL(f + 4) * Cdim)[lane];
                hv[q * 4 + 1] = (xb + (size_t)RL(f + 5) * Cdim)[lane];
                hv[q * 4 + 2] = (xb + (size_t)RL(f + 6) * Cdim)[lane];
                hv[q * 4 + 3] = (xb + (size_t)RL(f + 7) * Cdim)[lane];
            }
            // --- compute: weights broadcast + bilinear blend -------------
#pragma unroll
            for (int q = 0; q < 4; ++q) {
                const int f = (k * 8 + ih * 4 + q) * 8;
                float glt = __int_as_float(RL(f + 0));
                float grb = __int_as_float(RL(f + 1));
                float glb = __int_as_float(RL(f + 2));
                float grt = __int_as_float(RL(f + 3));
                float sv = glt * __half2float(hv[q * 4 + 0])
                         + grb * __half2float(hv[q * 4 + 1])
                         + glb * __half2float(hv[q * 4 + 2])
                         + grt * __half2float(hv[q * 4 + 3]);
                acc[ih * 4 + q] += wk9[k] * sv;
            }
        }
    }
#undef RL
#undef GV

#pragma unroll
    for (int i = 0; i < 8; ++i)
        accs_h[gu * 8 + i][lane] = (_Float16)acc[i];
    __syncthreads();

    // --- Phase B: MFMA pointwise --------------------------------------------
    {
        int pb = gu & 3;             // px tile (16 px)
        int ob = gu >> 2;            // oc block (32 oc = 2 tiles)
        int lr = lane & 15;
        int lg = lane >> 4;

        // A-frags: A[px][c], lane: row=lr, k = lg*8+j; k-steps 0 and 32
        const v8h a0 = *(const v8h*)&accs_h[pb * 16 + lr][lg * 8];
        const v8h a1 = *(const v8h*)&accs_h[pb * 16 + lr][32 + lg * 8];

        // B-frags from global c_pw: B[c][oc] = c_pw[oc*64+c];
        // lane: col = oc0+lr, k = lg*8+j  -> 8 contiguous floats of row oc0+lr
        v4f d0 = {0.f, 0.f, 0.f, 0.f}, d1 = {0.f, 0.f, 0.f, 0.f};
#pragma unroll
        for (int t = 0; t < 2; ++t) {
            int oc = ob * 32 + t * 16 + lr;
            const float* wr = c_pw + oc * Cdim + lg * 8;
            v8h b0, b1;
#pragma unroll
            for (int j = 0; j < 8; ++j) {
                b0[j] = (_Float16)wr[j];
                b1[j] = (_Float16)wr[32 + j];
            }
            if (t == 0) {
                d0 = __builtin_amdgcn_mfma_f32_16x16x32_f16(a0, b0, d0, 0, 0, 0);
                d0 = __builtin_amdgcn_mfma_f32_16x16x32_f16(a1, b1, d0, 0, 0, 0);
            } else {
                d1 = __builtin_amdgcn_mfma_f32_16x16x32_f16(a0, b0, d1, 0, 0, 0);
                d1 = __builtin_amdgcn_mfma_f32_16x16x32_f16(a1, b1, d1, 0, 0, 0);
            }
        }

        // D layout: row = lg*4 + r (px), col = lr (oc within tile)
#pragma unroll
        for (int r = 0; r < 4; ++r) {
            outD[pb * 16 + lg * 4 + r][ob * 32 + lr]      = d0[r];
            outD[pb * 16 + lg * 4 + r][ob * 32 + 16 + lr] = d1[r];
        }
    }
    __syncthreads();

    // --- coalesced NCHW store: lane = pixel, wave = oc group ---------------
    int pix = pix0 + lane;
    int hw  = pix & (HW - 1);
    size_t obase = (size_t)b * Cdim * HW + hw;
#pragma unroll
    for (int i = 0; i < 8; ++i)
        out[obase + (size_t)(gu * 8 + i) * HW] = outD[lane][gu * 8 + i];
}

extern "C" void kernel_launch(void* const* d_in, const int* in_sizes, int n_in,
                              void* d_out, int out_size, void* d_ws, size_t ws_size,
                              hipStream_t stream) {
    const float* x    = (const float*)d_in[0];
    const float* p_dw = (const float*)d_in[1];
    const float* p_pw = (const float*)d_in[2];
    const float* c_dw = (const float*)d_in[3];
    const float* c_pw = (const float*)d_in[4];
    float* out = (float*)d_out;

    __half* xt = (__half*)d_ws;                                 // 8.65 MB padded NHWC fp16
    float* geo = (float*)((char*)d_ws + (size_t)4 * HWp * Cdim * 2);  // 18.9 MB

    offset_geo_kernel<<<dim3(NBLK), dim3(512), 0, stream>>>(x, p_dw, p_pw, xt, geo);
    deform_kernel<<<dim3(NBLK), dim3(512), 0, stream>>>(xt, c_dw, c_pw, (const int*)geo, out);
}

// Round 18
// 58.226 us; speedup vs baseline: 1.0935x; 1.0935x over previous
//
#include <hip/hip_runtime.h>
#include <hip/hip_fp16.h>

#define Hdim 128
#define Wdim 128
#define Cdim 64
#define HW   (Hdim * Wdim)
#define NPIX (4 * HW)     // 65536
#define NBLK (NPIX / 64)  // 1024 blocks / tiles, 64 pixels each
#define NXCD 8
#define Hp 130            // padded dims
#define HWp (Hp * Hp)     // 16900

typedef _Float16 v8h __attribute__((ext_vector_type(8)));
typedef float    v4f __attribute__((ext_vector_type(4)));

// XCD-aware bijective swizzle (nwg % 8 == 0): consecutive logical blocks
// (which share image rows -> xt reuse) land on the SAME XCD's L2.
__device__ __forceinline__ int xcd_swizzle(int bid, int nblk) {
    return (bid % NXCD) * (nblk / NXCD) + bid / NXCD;
}

// geo layout: [group = pixel>>3][pair kp = k*8+i][4 dwords]:
//   d0 = half2(glt, grt)  col-iy0 weights (row ix0, row ix1)
//   d1 = half2(glb, grb)  col-iy0+1 weights
//   d2 = base1 = ix0*130+iy0,  d3 = base2 = ix1*130+iy0
// group stride 320 dwords (288 used; padded for the 5x64 prefetch).

// ---------------------------------------------------------------------------
// Kernel A: fused {NCHW->padded-NHWC-fp16 transpose} + {offset conv dw3x3 +
// pw 64->18} + {sampling geometry, pair-compressed}.
// ---------------------------------------------------------------------------
__global__ __launch_bounds__(512) void offset_geo_kernel(
    const float* __restrict__ x,     // (B, C, H, W)
    const float* __restrict__ p_dw,  // (C, 1, 3, 3)
    const float* __restrict__ p_pw,  // (18, C, 1, 1)
    __half* __restrict__ xt,         // (B, 130, 130, C) padded NHWC fp16
    unsigned int* __restrict__ geo)  // (8192, 320) dwords
{
    __shared__ float part[8][18][64];   // 36.8 KB; part[0] reused as sum

    int lane = threadIdx.x & 63;
    int g    = threadIdx.x >> 6;
    int blk  = xcd_swizzle(blockIdx.x, NBLK);
    int pix0 = blk * 64;
    int pix  = pix0 + lane;
    int w = pix & (Wdim - 1);
    int h = (pix >> 7) & (Hdim - 1);
    int b = pix >> 14;

    // --- zero the pad ring of xt (2064 ring positions x 128 B) -----------
    {
        int gid = blockIdx.x * 512 + threadIdx.x;   // raw id: blocks 0..32
        if (gid < 2064 * 8) {
            int rp  = gid >> 3, sub = gid & 7;
            int img = rp / 516, pos = rp - img * 516;
            int i, j;
            if (pos < 130)      { i = 0;   j = pos; }
            else if (pos < 260) { i = 129; j = pos - 130; }
            else { int p2 = pos - 260; i = 1 + (p2 >> 1); j = (p2 & 1) ? 129 : 0; }
            float4* dst = (float4*)(xt + ((size_t)img * HWp + i * Hp + j) * Cdim);
            dst[sub] = make_float4(0.f, 0.f, 0.f, 0.f);
        }
    }

    // --- depthwise 3x3: masks/offsets hoisted out of the channel loop ----
    int   off9[9];
    float msk9[9];
#pragma unroll
    for (int dh = -1; dh <= 1; ++dh) {
#pragma unroll
        for (int dw = -1; dw <= 1; ++dw) {
            int tap = (dh + 1) * 3 + (dw + 1);
            int hh = h + dh, ww = w + dw;
            bool ok = (hh >= 0) & (hh < Hdim) & (ww >= 0) & (ww < Wdim);
            off9[tap] = ok ? hh * Wdim + ww : 0;
            msk9[tap] = ok ? 1.f : 0.f;
        }
    }

    float t[8], ctr[8];
#pragma unroll
    for (int i = 0; i < 8; ++i) {
        int c = g * 8 + i;              // wave-uniform
        const float* xb = x + (size_t)(b * Cdim + c) * HW;
        float s = 0.f;
#pragma unroll
        for (int tap = 0; tap < 9; ++tap) {
            float v = xb[off9[tap]] * msk9[tap];
            s += v * p_dw[c * 9 + tap];
        }
        t[i]   = s;
        ctr[i] = xb[h * Wdim + w];      // transpose source (center tap)
    }

    // --- transpose write: 8 channels -> 4x half2 packed in one 16B store --
    {
        __half2 h0 = __floats2half2_rn(ctr[0], ctr[1]);
        __half2 h1 = __floats2half2_rn(ctr[2], ctr[3]);
        __half2 h2 = __floats2half2_rn(ctr[4], ctr[5]);
        __half2 h3 = __floats2half2_rn(ctr[6], ctr[7]);
        uint4 pk;
        pk.x = *(const unsigned int*)&h0;
        pk.y = *(const unsigned int*)&h1;
        pk.z = *(const unsigned int*)&h2;
        pk.w = *(const unsigned int*)&h3;
        size_t ppos = ((size_t)b * HWp + (h + 1) * Hp + (w + 1)) * Cdim + g * 8;
        *(uint4*)(xt + ppos) = pk;      // 16B-aligned (g*8 halves)
    }

    // --- pointwise 64->18 partials -> LDS ---------------------------------
#pragma unroll
    for (int j = 0; j < 18; ++j) {
        float s = 0.f;
#pragma unroll
        for (int i = 0; i < 8; ++i)
            s += p_pw[j * Cdim + g * 8 + i] * t[i];
        part[g][j][lane] = s;
    }
    __syncthreads();

    // reduce 8 partials into part[0]
#pragma unroll
    for (int it = 0; it < 3; ++it) {
        int idx = threadIdx.x + it * 512;
        if (idx < 18 * 64) {
            int j = idx >> 6;
            int p = idx & 63;
            float s = part[0][j][p];
#pragma unroll
            for (int q = 1; q < 8; ++q) s += part[q][j][p];
            part[0][j][p] = s;
        }
    }
    __syncthreads();

    // --- geometry pass: pair-compressed emission --------------------------
#pragma unroll
    for (int it = 0; it < 2; ++it) {
        int idx = threadIdx.x + it * 512;
        if (idx < 9 * 64) {
            int k = idx >> 6;
            int p = idx & 63;
            int ppix = pix0 + p;
            int pw2 = ppix & (Wdim - 1);
            int ph2 = (ppix >> 7) & (Hdim - 1);

            float px = (float)(ph2 + 1) + (float)(k / 3 - 1) + part[0][k][p];
            float py = (float)(pw2 + 1) + (float)(k % 3 - 1) + part[0][k + 9][p];

            float fx = floorf(px), fy = floorf(py);
            float ltx = fminf(fmaxf(fx, 0.f), 129.f);
            float lty = fminf(fmaxf(fy, 0.f), 129.f);
            float rbx = fminf(fmaxf(fx + 1.f, 0.f), 129.f);
            float rby = fminf(fmaxf(fy + 1.f, 0.f), 129.f);
            float pxc = fminf(fmaxf(px, 0.f), 129.f);
            float pyc = fminf(fmaxf(py, 0.f), 129.f);

            float glt = (1.f + ltx - pxc) * (1.f + lty - pyc);
            float grb = (1.f - rbx + pxc) * (1.f - rby + pyc);
            float glb = (1.f + ltx - pxc) * (1.f - rby + pyc);
            float grt = (1.f - rbx + pxc) * (1.f + lty - pyc);

            int ix0 = (int)ltx, iy0 = (int)lty, ix1 = (int)rbx, iy1 = (int)rby;

            int base1, base2;
            if (iy1 == iy0 + 1) {
                base1 = ix0 * Hp + iy0;     // row ltx, cols (iy0, iy0+1)
                base2 = ix1 * Hp + iy0;     // row rbx
            } else {
                // both cols collapsed onto the zero-pad ring -> contribution
                // is provably 0; zero weights, safe base.
                glt = glb = grt = grb = 0.f;
                base1 = base2 = 0;
            }

            __half2 wlo = __floats2half2_rn(glt, grt);   // col iy0
            __half2 whi = __floats2half2_rn(glb, grb);   // col iy0+1
            uint4 pk;
            pk.x = *(const unsigned int*)&wlo;
            pk.y = *(const unsigned int*)&whi;
            pk.z = (unsigned int)base1;
            pk.w = (unsigned int)base2;
            size_t e = ((size_t)blk * 8 + (p >> 3)) * 320 + (size_t)(k * 8 + (p & 7)) * 4;
            *(uint4*)(geo + e) = pk;
        }
    }
}

// ---------------------------------------------------------------------------
// Kernel B: deformable sampling + collapsed depthwise + MFMA pointwise.
// R18 = R16 base with pair-compressed gathers, confounds of R15 removed:
//   - per (pixel,k): TWO u32-per-lane loads (256B each = both bilinear cols
//     of one row; lo lanes = col iy0's 64ch as half2, hi lanes = col iy0+1)
//     -> 144 VMEM/wave vs 288 (testing the per-request-bound hypothesis).
//   - weight select: 1 cndmask of a pre-packed half2 + v_pk fp16 blend
//     (~12 VALU/pair vs R15's ~25).
//   - accs half2 writes at 4B stride over 32 lanes: conflict-free.
//   - geo = 4 dwords/entry -> 5-reg prefetch; VGPR ~60 keeps 8 waves/SIMD.
// Phase B: MFMA pointwise (unchanged from R16).
// ---------------------------------------------------------------------------
__global__ __launch_bounds__(512) void deform_kernel(
    const __half* __restrict__ xt,   // (B, 130, 130, C) padded NHWC fp16
    const float* __restrict__ c_dw,  // (C, 1, 3, 3)
    const float* __restrict__ c_pw,  // (C, C, 1, 1)
    const int* __restrict__ geo,     // (8192, 320) dwords
    float* __restrict__ out)         // (B, C, H, W)
{
    __shared__ _Float16 accs_h[64][72];  // [pixel][channel] 9.2 KB
    __shared__ float    outD[64][69];    // [pixel][oc] 17.6 KB

    int lane = threadIdx.x & 63;
    int c2   = lane & 31;            // channel pair -> channels 2c2, 2c2+1
    bool lo  = lane < 32;
    int gu   = __builtin_amdgcn_readfirstlane(threadIdx.x >> 6);
    int blk  = xcd_swizzle(blockIdx.x, NBLK);
    int pix0 = blk * 64;
    int b    = pix0 >> 14;           // block-uniform
    const __half* xb = xt + (size_t)b * HWp * Cdim;

    // prefetch this wave's geometry: 288 dwords -> 5 VGPRs per lane
    int gv0, gv1, gv2, gv3, gv4;
    {
        const int* gb = geo + ((size_t)blk * 8 + gu) * 320 + lane;
        gv0 = gb[0];   gv1 = gb[64];  gv2 = gb[128];
        gv3 = gb[192]; gv4 = gb[256];
    }
    // per-lane channel-pair depthwise weights
    float wkx9[9], wky9[9];
#pragma unroll
    for (int k = 0; k < 9; ++k) {
        wkx9[k] = c_dw[(2 * c2) * 9 + k];
        wky9[k] = c_dw[(2 * c2 + 1) * 9 + k];
    }

#define GV(r) ((r)==0?gv0:(r)==1?gv1:(r)==2?gv2:(r)==3?gv3:gv4)
#define RL(f) __builtin_amdgcn_readlane(GV((f) >> 6), (f) & 63)

    float2 acc2[8];
#pragma unroll
    for (int i = 0; i < 8; ++i) acc2[i] = make_float2(0.f, 0.f);

#pragma unroll
    for (int k = 0; k < 9; ++k) {
#pragma unroll
        for (int i = 0; i < 8; ++i) {
            const int f = (k * 8 + i) * 4;
            unsigned int d0 = (unsigned int)RL(f + 0);
            unsigned int d1 = (unsigned int)RL(f + 1);
            int bs1 = RL(f + 2);
            int bs2 = RL(f + 3);
            const unsigned int* p1 = (const unsigned int*)(xb + ((size_t)bs1 << 6));
            const unsigned int* p2 = (const unsigned int*)(xb + ((size_t)bs2 << 6));
            unsigned int v1 = p1[lane];  // 256B: both cols of row ix0
            unsigned int v2 = p2[lane];  // 256B: both cols of row ix1
            unsigned int wsu = lo ? d0 : d1;   // this half's packed weights
            __half2 w12 = *(const __half2*)&wsu;
            __half2 v1h = *(const __half2*)&v1;
            __half2 v2h = *(const __half2*)&v2;
            // t = v1*w_row0 + v2*w_row1   (packed fp16, per-channel pair)
            __half2 tt = __hadd2(__hmul2(v1h, __half2half2(__low2half(w12))),
                                 __hmul2(v2h, __half2half2(__high2half(w12))));
            float2 tf = __half22float2(tt);
            acc2[i].x += wkx9[k] * tf.x;   // half-partial; cross-half add below
            acc2[i].y += wky9[k] * tf.y;
        }
    }
#undef RL
#undef GV

    // cross-half reduction (each half held one bilinear column)
#pragma unroll
    for (int i = 0; i < 8; ++i) {
        acc2[i].x += __shfl_xor(acc2[i].x, 32);
        acc2[i].y += __shfl_xor(acc2[i].y, 32);
    }
    if (lo) {
#pragma unroll
        for (int i = 0; i < 8; ++i) {
            __half2 hv = __floats2half2_rn(acc2[i].x, acc2[i].y);
            *(__half2*)&accs_h[gu * 8 + i][2 * c2] = hv;   // 4B x 32 lanes: conflict-free
        }
    }
    __syncthreads();

    // --- Phase B: MFMA pointwise (R16) -------------------------------------
    {
        int pb = gu & 3;             // px tile (16 px)
        int ob = gu >> 2;            // oc block (32 oc = 2 tiles)
        int lr = lane & 15;
        int lg = lane >> 4;

        const v8h a0 = *(const v8h*)&accs_h[pb * 16 + lr][lg * 8];
        const v8h a1 = *(const v8h*)&accs_h[pb * 16 + lr][32 + lg * 8];

        v4f d0 = {0.f, 0.f, 0.f, 0.f}, d1 = {0.f, 0.f, 0.f, 0.f};
#pragma unroll
        for (int t = 0; t < 2; ++t) {
            int oc = ob * 32 + t * 16 + lr;
            const float* wr = c_pw + oc * Cdim + lg * 8;
            v8h b0, b1;
#pragma unroll
            for (int j = 0; j < 8; ++j) {
                b0[j] = (_Float16)wr[j];
                b1[j] = (_Float16)wr[32 + j];
            }
            if (t == 0) {
                d0 = __builtin_amdgcn_mfma_f32_16x16x32_f16(a0, b0, d0, 0, 0, 0);
                d0 = __builtin_amdgcn_mfma_f32_16x16x32_f16(a1, b1, d0, 0, 0, 0);
            } else {
                d1 = __builtin_amdgcn_mfma_f32_16x16x32_f16(a0, b0, d1, 0, 0, 0);
                d1 = __builtin_amdgcn_mfma_f32_16x16x32_f16(a1, b1, d1, 0, 0, 0);
            }
        }

        // D layout: row = lg*4 + r (px), col = lr (oc within tile)
#pragma unroll
        for (int r = 0; r < 4; ++r) {
            outD[pb * 16 + lg * 4 + r][ob * 32 + lr]      = d0[r];
            outD[pb * 16 + lg * 4 + r][ob * 32 + 16 + lr] = d1[r];
        }
    }
    __syncthreads();

    // --- coalesced NCHW store: lane = pixel, wave = oc group ---------------
    int pix = pix0 + lane;
    int hw  = pix & (HW - 1);
    size_t obase = (size_t)b * Cdim * HW + hw;
#pragma unroll
    for (int i = 0; i < 8; ++i)
        out[obase + (size_t)(gu * 8 + i) * HW] = outD[lane][gu * 8 + i];
}

extern "C" void kernel_launch(void* const* d_in, const int* in_sizes, int n_in,
                              void* d_out, int out_size, void* d_ws, size_t ws_size,
                              hipStream_t stream) {
    const float* x    = (const float*)d_in[0];
    const float* p_dw = (const float*)d_in[1];
    const float* p_pw = (const float*)d_in[2];
    const float* c_dw = (const float*)d_in[3];
    const float* c_pw = (const float*)d_in[4];
    float* out = (float*)d_out;

    __half* xt = (__half*)d_ws;                                 // 8.65 MB padded NHWC fp16
    unsigned int* geo = (unsigned int*)((char*)d_ws + (size_t)4 * HWp * Cdim * 2);  // 10.5 MB

    offset_geo_kernel<<<dim3(NBLK), dim3(512), 0, stream>>>(x, p_dw, p_pw, xt, geo);
    deform_kernel<<<dim3(NBLK), dim3(512), 0, stream>>>(xt, c_dw, c_pw, (const int*)geo, out);
}

// Round 19
// 54.517 us; speedup vs baseline: 1.1679x; 1.0680x over previous
//
#include <hip/hip_runtime.h>
#include <hip/hip_fp16.h>

#define Hdim 128
#define Wdim 128
#define Cdim 64
#define HW   (Hdim * Wdim)
#define NPIX (4 * HW)     // 65536
#define NBLK (NPIX / 64)  // 1024 blocks / tiles, 64 pixels each
#define NXCD 8
#define Hp 130            // padded dims
#define HWp (Hp * Hp)     // 16900

typedef _Float16 v8h __attribute__((ext_vector_type(8)));
typedef float    v4f __attribute__((ext_vector_type(4)));

// XCD-aware bijective swizzle (nwg % 8 == 0): consecutive logical blocks
// (which share image rows -> xt reuse) land on the SAME XCD's L2.
__device__ __forceinline__ int xcd_swizzle(int bid, int nblk) {
    return (bid % NXCD) * (nblk / NXCD) + bid / NXCD;
}

// ---------------------------------------------------------------------------
// Kernel 0: NCHW fp32 -> padded NHWC fp16 transpose + zero pad ring.
// (xt is the only cross-block-consumed tensor, so it needs its own kernel.)
// ---------------------------------------------------------------------------
__global__ __launch_bounds__(512) void transpose_kernel(
    const float* __restrict__ x,   // (B, C, H, W)
    __half* __restrict__ xt)       // (B, 130, 130, C) fp16
{
    __shared__ float tile[64][65];
    int lane = threadIdx.x & 63;
    int g    = threadIdx.x >> 6;
    int blk  = xcd_swizzle(blockIdx.x, NBLK);
    int pix0 = blk * 64;
    int b    = pix0 >> 14;
    int hw0  = pix0 & (HW - 1);
    int h    = hw0 >> 7;           // all 64 px of a block share one row
    int w0   = hw0 & 127;

    // zero the pad ring (2064 ring positions x 128 B)
    {
        int gid = blockIdx.x * 512 + threadIdx.x;   // raw id: blocks 0..32
        if (gid < 2064 * 8) {
            int rp  = gid >> 3, sub = gid & 7;
            int img = rp / 516, pos = rp - img * 516;
            int i, j;
            if (pos < 130)      { i = 0;   j = pos; }
            else if (pos < 260) { i = 129; j = pos - 130; }
            else { int p2 = pos - 260; i = 1 + (p2 >> 1); j = (p2 & 1) ? 129 : 0; }
            float4* dst = (float4*)(xt + ((size_t)img * HWp + i * Hp + j) * Cdim);
            dst[sub] = make_float4(0.f, 0.f, 0.f, 0.f);
        }
    }

#pragma unroll
    for (int i = 0; i < 8; ++i) {
        int c = g * 8 + i;
        tile[c][lane] = x[(size_t)(b * Cdim + c) * HW + hw0 + lane];
    }
    __syncthreads();
    // write: lane = channel; 128B contiguous per pixel
#pragma unroll
    for (int i = 0; i < 8; ++i) {
        int p = g * 8 + i;
        size_t ppos = ((size_t)b * HWp + (h + 1) * Hp + (w0 + 1 + p)) * Cdim + lane;
        xt[ppos] = (__half)tile[lane][p];
    }
}

// ---------------------------------------------------------------------------
// Kernel 1: FUSED {offset conv dw3x3 + pw 64->18} + {sampling geometry in
// LDS} + {deformable sampling, pair-compressed} + {MFMA pointwise}.
// geo never touches global memory (R18 round-tripped 21 MB through L2);
// one kernel launch + the geo prefetch latency eliminated.
// LDS: geoL 10.2 KB + 26.9 KB union{part_h | accs_h+outD} = 37.1 KB
// -> 4 blocks/CU (148 KB of 160).
// ---------------------------------------------------------------------------
__global__ __launch_bounds__(512) void fused_kernel(
    const float* __restrict__ x,     // (B, C, H, W)
    const float* __restrict__ p_dw,  // (C, 1, 3, 3)
    const float* __restrict__ p_pw,  // (18, C, 1, 1)
    const __half* __restrict__ xt,   // (B, 130, 130, C) fp16
    const float* __restrict__ c_dw,  // (C, 1, 3, 3)
    const float* __restrict__ c_pw,  // (C, C, 1, 1)
    float* __restrict__ out)         // (B, C, H, W)
{
    __shared__ __align__(16) unsigned char smem[26880];
    __shared__ __align__(16) unsigned int geoL[8][320];   // 10.24 KB

    auto part_h = (_Float16 (*)[18][64])smem;    // [8][18][64] fp16, 18.4 KB
    auto accs_h = (_Float16 (*)[72])smem;        // [64][72] fp16, 9.2 KB
    auto outD   = (float (*)[69])(smem + 9216);  // [64][69] f32, 17.7 KB

    int lane = threadIdx.x & 63;
    int g    = threadIdx.x >> 6;
    int blk  = xcd_swizzle(blockIdx.x, NBLK);
    int pix0 = blk * 64;
    int pix  = pix0 + lane;
    int w = pix & (Wdim - 1);
    int h = (pix >> 7) & (Hdim - 1);
    int b = pix >> 14;

    // --- phase 1: depthwise 3x3 stencil from x (masks hoisted) -----------
    int   off9[9];
    float msk9[9];
#pragma unroll
    for (int dh = -1; dh <= 1; ++dh) {
#pragma unroll
        for (int dw = -1; dw <= 1; ++dw) {
            int tap = (dh + 1) * 3 + (dw + 1);
            int hh = h + dh, ww = w + dw;
            bool ok = (hh >= 0) & (hh < Hdim) & (ww >= 0) & (ww < Wdim);
            off9[tap] = ok ? hh * Wdim + ww : 0;
            msk9[tap] = ok ? 1.f : 0.f;
        }
    }

    float t[8];
#pragma unroll
    for (int i = 0; i < 8; ++i) {
        int c = g * 8 + i;              // wave-uniform
        const float* xb0 = x + (size_t)(b * Cdim + c) * HW;
        float s = 0.f;
#pragma unroll
        for (int tap = 0; tap < 9; ++tap) {
            float v = xb0[off9[tap]] * msk9[tap];
            s += v * p_dw[c * 9 + tap];
        }
        t[i] = s;
    }

    // --- phase 2: pointwise 64->18 partials -> LDS (fp16) -----------------
#pragma unroll
    for (int j = 0; j < 18; ++j) {
        float s = 0.f;
#pragma unroll
        for (int i = 0; i < 8; ++i)
            s += p_pw[j * Cdim + g * 8 + i] * t[i];
        part_h[g][j][lane] = (_Float16)s;
    }
    __syncthreads();

    // --- phase 3: reduce 8 partials into part_h[0] ------------------------
#pragma unroll
    for (int it = 0; it < 3; ++it) {
        int idx = threadIdx.x + it * 512;
        if (idx < 18 * 64) {
            int j = idx >> 6;
            int p = idx & 63;
            float s = 0.f;
#pragma unroll
            for (int q = 0; q < 8; ++q) s += (float)part_h[q][j][p];
            part_h[0][j][p] = (_Float16)s;
        }
    }
    __syncthreads();

    // --- phase 4: geometry pass -> geoL (pair-compressed) -----------------
#pragma unroll
    for (int it = 0; it < 2; ++it) {
        int idx = threadIdx.x + it * 512;
        if (idx < 9 * 64) {
            int k = idx >> 6;
            int p = idx & 63;
            int ppix = pix0 + p;
            int pw2 = ppix & (Wdim - 1);
            int ph2 = (ppix >> 7) & (Hdim - 1);

            float px = (float)(ph2 + 1) + (float)(k / 3 - 1) + (float)part_h[0][k][p];
            float py = (float)(pw2 + 1) + (float)(k % 3 - 1) + (float)part_h[0][k + 9][p];

            float fx = floorf(px), fy = floorf(py);
            float ltx = fminf(fmaxf(fx, 0.f), 129.f);
            float lty = fminf(fmaxf(fy, 0.f), 129.f);
            float rbx = fminf(fmaxf(fx + 1.f, 0.f), 129.f);
            float rby = fminf(fmaxf(fy + 1.f, 0.f), 129.f);
            float pxc = fminf(fmaxf(px, 0.f), 129.f);
            float pyc = fminf(fmaxf(py, 0.f), 129.f);

            float glt = (1.f + ltx - pxc) * (1.f + lty - pyc);
            float grb = (1.f - rbx + pxc) * (1.f - rby + pyc);
            float glb = (1.f + ltx - pxc) * (1.f - rby + pyc);
            float grt = (1.f - rbx + pxc) * (1.f + lty - pyc);

            int ix0 = (int)ltx, iy0 = (int)lty, ix1 = (int)rbx, iy1 = (int)rby;

            int base1, base2;
            if (iy1 == iy0 + 1) {
                base1 = ix0 * Hp + iy0;     // row ltx, cols (iy0, iy0+1)
                base2 = ix1 * Hp + iy0;     // row rbx
            } else {
                glt = glb = grt = grb = 0.f;   // both cols on zero ring
                base1 = base2 = 0;
            }

            __half2 wlo = __floats2half2_rn(glt, grt);   // col iy0
            __half2 whi = __floats2half2_rn(glb, grb);   // col iy0+1
            uint4 pk;
            pk.x = *(const unsigned int*)&wlo;
            pk.y = *(const unsigned int*)&whi;
            pk.z = (unsigned int)base1;
            pk.w = (unsigned int)base2;
            *(uint4*)&geoL[p >> 3][(k * 8 + (p & 7)) * 4] = pk;
        }
    }
    __syncthreads();   // geoL ready; part region now dead -> reusable

    // --- phase 5: pair-compressed sampling (R18) --------------------------
    int c2   = lane & 31;
    bool lo  = lane < 32;
    int gu   = __builtin_amdgcn_readfirstlane(g);
    const __half* xb = xt + (size_t)b * HWp * Cdim;

    int gv0, gv1, gv2, gv3, gv4;
    {
        const unsigned int* gb = &geoL[gu][0] + lane;
        gv0 = gb[0];   gv1 = gb[64];  gv2 = gb[128];
        gv3 = gb[192]; gv4 = gb[256];
    }
    float wkx9[9], wky9[9];
#pragma unroll
    for (int k = 0; k < 9; ++k) {
        wkx9[k] = c_dw[(2 * c2) * 9 + k];
        wky9[k] = c_dw[(2 * c2 + 1) * 9 + k];
    }

#define GV(r) ((r)==0?gv0:(r)==1?gv1:(r)==2?gv2:(r)==3?gv3:gv4)
#define RL(f) __builtin_amdgcn_readlane(GV((f) >> 6), (f) & 63)

    float2 acc2[8];
#pragma unroll
    for (int i = 0; i < 8; ++i) acc2[i] = make_float2(0.f, 0.f);

#pragma unroll
    for (int k = 0; k < 9; ++k) {
#pragma unroll
        for (int i = 0; i < 8; ++i) {
            const int f = (k * 8 + i) * 4;
            unsigned int d0 = (unsigned int)RL(f + 0);
            unsigned int d1 = (unsigned int)RL(f + 1);
            int bs1 = RL(f + 2);
            int bs2 = RL(f + 3);
            const unsigned int* p1 = (const unsigned int*)(xb + ((size_t)bs1 << 6));
            const unsigned int* p2 = (const unsigned int*)(xb + ((size_t)bs2 << 6));
            unsigned int v1 = p1[lane];
            unsigned int v2 = p2[lane];
            unsigned int wsu = lo ? d0 : d1;
            __half2 w12 = *(const __half2*)&wsu;
            __half2 v1h = *(const __half2*)&v1;
            __half2 v2h = *(const __half2*)&v2;
            __half2 tt = __hadd2(__hmul2(v1h, __half2half2(__low2half(w12))),
                                 __hmul2(v2h, __half2half2(__high2half(w12))));
            float2 tf = __half22float2(tt);
            acc2[i].x += wkx9[k] * tf.x;
            acc2[i].y += wky9[k] * tf.y;
        }
    }
#undef RL
#undef GV

#pragma unroll
    for (int i = 0; i < 8; ++i) {
        acc2[i].x += __shfl_xor(acc2[i].x, 32);
        acc2[i].y += __shfl_xor(acc2[i].y, 32);
    }
    if (lo) {
#pragma unroll
        for (int i = 0; i < 8; ++i) {
            __half2 hv = __floats2half2_rn(acc2[i].x, acc2[i].y);
            *(__half2*)&accs_h[gu * 8 + i][2 * c2] = hv;
        }
    }
    __syncthreads();

    // --- phase 6: MFMA pointwise ------------------------------------------
    {
        int pb = gu & 3;
        int ob = gu >> 2;
        int lr = lane & 15;
        int lg = lane >> 4;

        const v8h a0 = *(const v8h*)&accs_h[pb * 16 + lr][lg * 8];
        const v8h a1 = *(const v8h*)&accs_h[pb * 16 + lr][32 + lg * 8];

        v4f d0 = {0.f, 0.f, 0.f, 0.f}, d1 = {0.f, 0.f, 0.f, 0.f};
#pragma unroll
        for (int t2 = 0; t2 < 2; ++t2) {
            int oc = ob * 32 + t2 * 16 + lr;
            const float* wr = c_pw + oc * Cdim + lg * 8;
            v8h b0, b1;
#pragma unroll
            for (int j = 0; j < 8; ++j) {
                b0[j] = (_Float16)wr[j];
                b1[j] = (_Float16)wr[32 + j];
            }
            if (t2 == 0) {
                d0 = __builtin_amdgcn_mfma_f32_16x16x32_f16(a0, b0, d0, 0, 0, 0);
                d0 = __builtin_amdgcn_mfma_f32_16x16x32_f16(a1, b1, d0, 0, 0, 0);
            } else {
                d1 = __builtin_amdgcn_mfma_f32_16x16x32_f16(a0, b0, d1, 0, 0, 0);
                d1 = __builtin_amdgcn_mfma_f32_16x16x32_f16(a1, b1, d1, 0, 0, 0);
            }
        }

#pragma unroll
        for (int r = 0; r < 4; ++r) {
            outD[pb * 16 + lg * 4 + r][ob * 32 + lr]      = d0[r];
            outD[pb * 16 + lg * 4 + r][ob * 32 + 16 + lr] = d1[r];
        }
    }
    __syncthreads();

    // --- phase 7: coalesced NCHW store ------------------------------------
    int hw = pix & (HW - 1);
    size_t obase = (size_t)b * Cdim * HW + hw;
#pragma unroll
    for (int i = 0; i < 8; ++i)
        out[obase + (size_t)(gu * 8 + i) * HW] = outD[lane][gu * 8 + i];
}

extern "C" void kernel_launch(void* const* d_in, const int* in_sizes, int n_in,
                              void* d_out, int out_size, void* d_ws, size_t ws_size,
                              hipStream_t stream) {
    const float* x    = (const float*)d_in[0];
    const float* p_dw = (const float*)d_in[1];
    const float* p_pw = (const float*)d_in[2];
    const float* c_dw = (const float*)d_in[3];
    const float* c_pw = (const float*)d_in[4];
    float* out = (float*)d_out;

    __half* xt = (__half*)d_ws;   // 8.65 MB padded NHWC fp16

    transpose_kernel<<<dim3(NBLK), dim3(512), 0, stream>>>(x, xt);
    fused_kernel<<<dim3(NBLK), dim3(512), 0, stream>>>(x, p_dw, p_pw, xt, c_dw, c_pw, out);
}

// Round 20
// 50.881 us; speedup vs baseline: 1.2514x; 1.0715x over previous
//
#include <hip/hip_runtime.h>
#include <hip/hip_fp16.h>

#define Hdim 128
#define Wdim 128
#define Cdim 64
#define HW   (Hdim * Wdim)
#define NPIX (4 * HW)     // 65536
#define NBLK (NPIX / 64)  // 1024 blocks / tiles, 64 pixels each
#define NXCD 8
#define Hp 130            // padded dims
#define HWp (Hp * Hp)     // 16900

typedef _Float16 v8h __attribute__((ext_vector_type(8)));
typedef float    v4f __attribute__((ext_vector_type(4)));

// XCD-aware bijective swizzle (nwg % 8 == 0): consecutive logical blocks
// (which share image rows -> xt reuse) land on the SAME XCD's L2.
__device__ __forceinline__ int xcd_swizzle(int bid, int nblk) {
    return (bid % NXCD) * (nblk / NXCD) + bid / NXCD;
}

// ---------------------------------------------------------------------------
// Kernel 0: NCHW fp32 -> padded NHWC fp16 transpose + zero pad ring.
// At HBM roofline (~25 MB @ ~6 TB/s ~= 4.2us). Unchanged from R19.
// ---------------------------------------------------------------------------
__global__ __launch_bounds__(512) void transpose_kernel(
    const float* __restrict__ x,   // (B, C, H, W)
    __half* __restrict__ xt)       // (B, 130, 130, C) fp16
{
    __shared__ float tile[64][65];
    int lane = threadIdx.x & 63;
    int g    = threadIdx.x >> 6;
    int blk  = xcd_swizzle(blockIdx.x, NBLK);
    int pix0 = blk * 64;
    int b    = pix0 >> 14;
    int hw0  = pix0 & (HW - 1);
    int h    = hw0 >> 7;           // all 64 px of a block share one row
    int w0   = hw0 & 127;

    // zero the pad ring (2064 ring positions x 128 B)
    {
        int gid = blockIdx.x * 512 + threadIdx.x;   // raw id: blocks 0..32
        if (gid < 2064 * 8) {
            int rp  = gid >> 3, sub = gid & 7;
            int img = rp / 516, pos = rp - img * 516;
            int i, j;
            if (pos < 130)      { i = 0;   j = pos; }
            else if (pos < 260) { i = 129; j = pos - 130; }
            else { int p2 = pos - 260; i = 1 + (p2 >> 1); j = (p2 & 1) ? 129 : 0; }
            float4* dst = (float4*)(xt + ((size_t)img * HWp + i * Hp + j) * Cdim);
            dst[sub] = make_float4(0.f, 0.f, 0.f, 0.f);
        }
    }

#pragma unroll
    for (int i = 0; i < 8; ++i) {
        int c = g * 8 + i;
        tile[c][lane] = x[(size_t)(b * Cdim + c) * HW + hw0 + lane];
    }
    __syncthreads();
#pragma unroll
    for (int i = 0; i < 8; ++i) {
        int p = g * 8 + i;
        size_t ppos = ((size_t)b * HWp + (h + 1) * Hp + (w0 + 1 + p)) * Cdim + lane;
        xt[ppos] = (__half)tile[lane][p];
    }
}

// ---------------------------------------------------------------------------
// Kernel 1: FUSED. R20 VALU-cut over R19:
//  - reduce pass merged into geometry pass (one fewer barrier + LDS pass)
//  - geo bases stored as PRE-SHIFTED byte offsets (addr math -> SALU)
//  - packed-fp16 blend AND accumulate (hfma2; ~11 VALU/pair vs ~16)
//  - packed cross-half reduce (1 shfl + 1 hadd2 per i)
// ---------------------------------------------------------------------------
__global__ __launch_bounds__(512) void fused_kernel(
    const float* __restrict__ x,     // (B, C, H, W)
    const float* __restrict__ p_dw,  // (C, 1, 3, 3)
    const float* __restrict__ p_pw,  // (18, C, 1, 1)
    const __half* __restrict__ xt,   // (B, 130, 130, C) fp16
    const float* __restrict__ c_dw,  // (C, 1, 3, 3)
    const float* __restrict__ c_pw,  // (C, C, 1, 1)
    float* __restrict__ out)         // (B, C, H, W)
{
    __shared__ __align__(16) unsigned char smem[26880];
    __shared__ __align__(16) unsigned int geoL[8][320];   // 10.24 KB

    auto part_h = (_Float16 (*)[18][64])smem;    // [8][18][64] fp16, 18.4 KB
    auto accs_h = (_Float16 (*)[72])smem;        // [64][72] fp16, 9.2 KB
    auto outD   = (float (*)[69])(smem + 9216);  // [64][69] f32, 17.7 KB

    int lane = threadIdx.x & 63;
    int g    = threadIdx.x >> 6;
    int blk  = xcd_swizzle(blockIdx.x, NBLK);
    int pix0 = blk * 64;
    int pix  = pix0 + lane;
    int w = pix & (Wdim - 1);
    int h = (pix >> 7) & (Hdim - 1);
    int b = pix >> 14;

    // --- phase 1: depthwise 3x3 stencil from x (masks hoisted) -----------
    int   off9[9];
    float msk9[9];
#pragma unroll
    for (int dh = -1; dh <= 1; ++dh) {
#pragma unroll
        for (int dw = -1; dw <= 1; ++dw) {
            int tap = (dh + 1) * 3 + (dw + 1);
            int hh = h + dh, ww = w + dw;
            bool ok = (hh >= 0) & (hh < Hdim) & (ww >= 0) & (ww < Wdim);
            off9[tap] = ok ? hh * Wdim + ww : 0;
            msk9[tap] = ok ? 1.f : 0.f;
        }
    }

    float t[8];
#pragma unroll
    for (int i = 0; i < 8; ++i) {
        int c = g * 8 + i;              // wave-uniform
        const float* xb0 = x + (size_t)(b * Cdim + c) * HW;
        float s = 0.f;
#pragma unroll
        for (int tap = 0; tap < 9; ++tap) {
            float v = xb0[off9[tap]] * msk9[tap];
            s += v * p_dw[c * 9 + tap];
        }
        t[i] = s;
    }

    // --- phase 2: pointwise 64->18 partials -> LDS (fp16) -----------------
#pragma unroll
    for (int j = 0; j < 18; ++j) {
        float s = 0.f;
#pragma unroll
        for (int i = 0; i < 8; ++i)
            s += p_pw[j * Cdim + g * 8 + i] * t[i];
        part_h[g][j][lane] = (_Float16)s;
    }
    __syncthreads();

    // --- phase 3: geometry pass (reduce folded in) -> geoL ----------------
#pragma unroll
    for (int it = 0; it < 2; ++it) {
        int idx = threadIdx.x + it * 512;
        if (idx < 9 * 64) {
            int k = idx >> 6;
            int p = idx & 63;

            float offx = 0.f, offy = 0.f;
#pragma unroll
            for (int q = 0; q < 8; ++q) {
                offx += (float)part_h[q][k][p];
                offy += (float)part_h[q][k + 9][p];
            }

            int ppix = pix0 + p;
            int pw2 = ppix & (Wdim - 1);
            int ph2 = (ppix >> 7) & (Hdim - 1);

            float px = (float)(ph2 + 1) + (float)(k / 3 - 1) + offx;
            float py = (float)(pw2 + 1) + (float)(k % 3 - 1) + offy;

            float fx = floorf(px), fy = floorf(py);
            float ltx = fminf(fmaxf(fx, 0.f), 129.f);
            float lty = fminf(fmaxf(fy, 0.f), 129.f);
            float rbx = fminf(fmaxf(fx + 1.f, 0.f), 129.f);
            float rby = fminf(fmaxf(fy + 1.f, 0.f), 129.f);
            float pxc = fminf(fmaxf(px, 0.f), 129.f);
            float pyc = fminf(fmaxf(py, 0.f), 129.f);

            float glt = (1.f + ltx - pxc) * (1.f + lty - pyc);
            float grb = (1.f - rbx + pxc) * (1.f - rby + pyc);
            float glb = (1.f + ltx - pxc) * (1.f - rby + pyc);
            float grt = (1.f - rbx + pxc) * (1.f + lty - pyc);

            int ix0 = (int)ltx, iy0 = (int)lty, ix1 = (int)rbx, iy1 = (int)rby;

            unsigned int bb1, bb2;
            if (iy1 == iy0 + 1) {
                bb1 = (unsigned int)(ix0 * Hp + iy0) << 7;  // byte offset (x128)
                bb2 = (unsigned int)(ix1 * Hp + iy0) << 7;
            } else {
                glt = glb = grt = grb = 0.f;   // both cols on zero ring
                bb1 = bb2 = 0;
            }

            __half2 wlo = __floats2half2_rn(glt, grt);   // col iy0: (row0, row1)
            __half2 whi = __floats2half2_rn(glb, grb);   // col iy0+1
            uint4 pk;
            pk.x = *(const unsigned int*)&wlo;
            pk.y = *(const unsigned int*)&whi;
            pk.z = bb1;
            pk.w = bb2;
            *(uint4*)&geoL[p >> 3][(k * 8 + (p & 7)) * 4] = pk;
        }
    }
    __syncthreads();   // geoL ready; part region now dead -> reusable

    // --- phase 4: pair-compressed sampling, packed fp16 -------------------
    int c2   = lane & 31;
    bool lo  = lane < 32;
    int gu   = __builtin_amdgcn_readfirstlane(g);
    const char* xbB = (const char*)(xt + (size_t)b * HWp * Cdim) + (lane << 2);

    int gv0, gv1, gv2, gv3, gv4;
    {
        const unsigned int* gb = &geoL[gu][0] + lane;
        gv0 = gb[0];   gv1 = gb[64];  gv2 = gb[128];
        gv3 = gb[192]; gv4 = gb[256];
    }
    __half2 wk2h[9];
#pragma unroll
    for (int k = 0; k < 9; ++k)
        wk2h[k] = __floats2half2_rn(c_dw[(2 * c2) * 9 + k],
                                    c_dw[(2 * c2 + 1) * 9 + k]);

#define GV(r) ((r)==0?gv0:(r)==1?gv1:(r)==2?gv2:(r)==3?gv3:gv4)
#define RL(f) __builtin_amdgcn_readlane(GV((f) >> 6), (f) & 63)

    __half2 acch[8];
#pragma unroll
    for (int i = 0; i < 8; ++i) acch[i] = __floats2half2_rn(0.f, 0.f);

#pragma unroll
    for (int k = 0; k < 9; ++k) {
#pragma unroll
        for (int i = 0; i < 8; ++i) {
            const int f = (k * 8 + i) * 4;
            unsigned int d0 = (unsigned int)RL(f + 0);
            unsigned int d1 = (unsigned int)RL(f + 1);
            unsigned int bb1 = (unsigned int)RL(f + 2);
            unsigned int bb2 = (unsigned int)RL(f + 3);
            unsigned int v1 = *(const unsigned int*)(xbB + bb1);  // row ix0
            unsigned int v2 = *(const unsigned int*)(xbB + bb2);  // row ix1
            unsigned int wsu = lo ? d0 : d1;      // this half's packed weights
            __half2 w12 = *(const __half2*)&wsu;  // (w_row0, w_row1)
            __half2 v1h = *(const __half2*)&v1;
            __half2 v2h = *(const __half2*)&v2;
            __half2 tt = __hfma2(v2h, __half2half2(__high2half(w12)),
                                 __hmul2(v1h, __half2half2(__low2half(w12))));
            acch[i] = __hfma2(wk2h[k], tt, acch[i]);
        }
    }
#undef RL
#undef GV

    // cross-half reduction, packed (both halves end with the full sum)
#pragma unroll
    for (int i = 0; i < 8; ++i) {
        int me = *(int*)&acch[i];
        int ot = __shfl_xor(me, 32);
        acch[i] = __hadd2(acch[i], *(__half2*)&ot);
    }
    if (lo) {
#pragma unroll
        for (int i = 0; i < 8; ++i)
            *(__half2*)&accs_h[gu * 8 + i][2 * c2] = acch[i];
    }
    __syncthreads();

    // --- phase 5: MFMA pointwise ------------------------------------------
    {
        int pb = gu & 3;
        int ob = gu >> 2;
        int lr = lane & 15;
        int lg = lane >> 4;

        const v8h a0 = *(const v8h*)&accs_h[pb * 16 + lr][lg * 8];
        const v8h a1 = *(const v8h*)&accs_h[pb * 16 + lr][32 + lg * 8];

        v4f d0 = {0.f, 0.f, 0.f, 0.f}, d1 = {0.f, 0.f, 0.f, 0.f};
#pragma unroll
        for (int t2 = 0; t2 < 2; ++t2) {
            int oc = ob * 32 + t2 * 16 + lr;
            const float* wr = c_pw + oc * Cdim + lg * 8;
            v8h b0, b1;
#pragma unroll
            for (int j = 0; j < 8; ++j) {
                b0[j] = (_Float16)wr[j];
                b1[j] = (_Float16)wr[32 + j];
            }
            if (t2 == 0) {
                d0 = __builtin_amdgcn_mfma_f32_16x16x32_f16(a0, b0, d0, 0, 0, 0);
                d0 = __builtin_amdgcn_mfma_f32_16x16x32_f16(a1, b1, d0, 0, 0, 0);
            } else {
                d1 = __builtin_amdgcn_mfma_f32_16x16x32_f16(a0, b0, d1, 0, 0, 0);
                d1 = __builtin_amdgcn_mfma_f32_16x16x32_f16(a1, b1, d1, 0, 0, 0);
            }
        }

#pragma unroll
        for (int r = 0; r < 4; ++r) {
            outD[pb * 16 + lg * 4 + r][ob * 32 + lr]      = d0[r];
            outD[pb * 16 + lg * 4 + r][ob * 32 + 16 + lr] = d1[r];
        }
    }
    __syncthreads();

    // --- phase 6: coalesced NCHW store ------------------------------------
    int hw = pix & (HW - 1);
    size_t obase = (size_t)b * Cdim * HW + hw;
#pragma unroll
    for (int i = 0; i < 8; ++i)
        out[obase + (size_t)(gu * 8 + i) * HW] = outD[lane][gu * 8 + i];
}

extern "C" void kernel_launch(void* const* d_in, const int* in_sizes, int n_in,
                              void* d_out, int out_size, void* d_ws, size_t ws_size,
                              hipStream_t stream) {
    const float* x    = (const float*)d_in[0];
    const float* p_dw = (const float*)d_in[1];
    const float* p_pw = (const float*)d_in[2];
    const float* c_dw = (const float*)d_in[3];
    const float* c_pw = (const float*)d_in[4];
    float* out = (float*)d_out;

    __half* xt = (__half*)d_ws;   // 8.65 MB padded NHWC fp16

    transpose_kernel<<<dim3(NBLK), dim3(512), 0, stream>>>(x, xt);
    fused_kernel<<<dim3(NBLK), dim3(512), 0, stream>>>(x, p_dw, p_pw, xt, c_dw, c_pw, out);
}